// Round 11
// baseline (843.524 us; speedup 1.0000x reference)
//
#include <hip/hip_runtime.h>

// out[b,n,f] = sum_{l,m} x1[b,l,f] * x2[b,m,f] * cg[l,m,n]
// B=50000, d1=d2=9, d3=25, MUL=512, fp32 in/out.
//
// MFMA formulation: per b, out[n,f] = sum_k W[k,n]*S[k,f], k=(l,m) pad 96;
// S=x1*x2 bf16 in LDS (row per f-channel, pitch 208B); W=cg bf16 regs;
// mfma_f32_16x16x32_bf16 fp32-accum. ZERO barriers: wave w's threads
// (t=64w..64w+63) write S rows 2t,2t+1 = [128w,128w+128) -- exactly the
// rows wave w's MFMA reads. Per-wave DS ops are in program order.
//
// Ledger: R7 858 (dword loads/stores, 3 blk/CU); R8 874 (L2 stores);
// R9 885 (2-deep prefetch); R10 831 (per-wave transpose, scalar-NT quads).
// Theory: every ~6.3TB/s reference moves 8-16B/lane contiguous; our 4B/lane
// widths are the limiter. R11: width everywhere --
//   loads:  2 channels/thread -> float2 (8B/lane, 512B/instr)
//   stores: transposed tile -> ONE f32x4 NT store/thread (16B/lane,
//           2x512B contiguous segments per wave-instr)
// Cost: FCHUNK=512 -> LDS 106.5KB -> 1 blk/CU (4 waves, 12.5% occ).
// Fill evidence: 78% HBM at 11% occ -> acceptable for streams.

#define BATCH 50000
#define MUL   512
#define D3    25
#define ROWB  208              // 104 bf16: 96 K + 8 pad (16B-aligned rows)
#define TROW  132              // transpose tile pitch: 528B=33x16B, %128=16
#define RPB   10
#define SMEM_BYTES (512 * ROWB)

typedef __bf16 bf16x8 __attribute__((ext_vector_type(8)));
typedef float  f32x4  __attribute__((ext_vector_type(4)));

__global__ void __launch_bounds__(256) tp_kernel(
    const float* __restrict__ x1,
    const float* __restrict__ x2,
    const float* __restrict__ cg,
    float* __restrict__ out) {

    extern __shared__ char smem[];

    const int bg   = blockIdx.x;
    const int tid  = threadIdx.x;
    const int lane = tid & 63;
    const int wv   = tid >> 6;
    const int b0   = bg * RPB;

    // thread owns channels f0=2*tid, f1=2*tid+1 for the load/product phase
    const float2* x1v = reinterpret_cast<const float2*>(
                            x1 + (size_t)b0 * (9 * MUL)) + tid;
    const float2* x2v = reinterpret_cast<const float2*>(
                            x2 + (size_t)b0 * (9 * MUL)) + tid;

    float2 a[9], c[9];
    #pragma unroll
    for (int l = 0; l < 9; ++l) a[l] = x1v[l * 256];
    #pragma unroll
    for (int m = 0; m < 9; ++m) c[m] = x2v[m * 256];

    // ---- W fragments once per block ----
    // A[mt][ks]: row n = 16*mt + (lane&15), k = 32*ks + 8*(lane>>4) + j
    bf16x8 afrag[2][3];
    #pragma unroll
    for (int mt = 0; mt < 2; ++mt) {
        const int n = 16 * mt + (lane & 15);
        #pragma unroll
        for (int ks = 0; ks < 3; ++ks) {
            #pragma unroll
            for (int j = 0; j < 8; ++j) {
                const int k = 32 * ks + 8 * (lane >> 4) + j;
                float w = (k < 81 && n < D3) ? cg[k * D3 + n] : 0.0f;
                afrag[mt][ks][j] = (__bf16)w;
            }
        }
    }

    // per-wave output base: wave wv owns f in [128*wv, 128*wv+128)
    float* op = out + (size_t)b0 * (D3 * MUL) + wv * 128;

    uint4* row0 = reinterpret_cast<uint4*>(smem + (size_t)tid * (2 * ROWB));
    uint4* row1 = reinterpret_cast<uint4*>(smem + (size_t)tid * (2 * ROWB) + ROWB);
    const char* bbase0 = smem + (size_t)(wv * 128 + (lane & 15)) * ROWB
                              + (lane >> 4) * 16;
    // wave's private region reused as transposed fp32 tile [25][TROW]
    float* twave = reinterpret_cast<float*>(smem + (size_t)wv * 128 * ROWB);

    for (int r = 0; r < RPB; ++r) {
        // ---- S products -> bf16 -> 2 own LDS rows ----
        #pragma unroll
        for (int ch = 0; ch < 12; ++ch) {
            bf16x8 v0, v1;
            #pragma unroll
            for (int j = 0; j < 8; ++j) {
                const int k = ch * 8 + j;
                float plo = 0.0f, phi = 0.0f;
                if (k < 81) {
                    plo = a[k / 9].x * c[k % 9].x;
                    phi = a[k / 9].y * c[k % 9].y;
                }
                v0[j] = (__bf16)plo;
                v1[j] = (__bf16)phi;
            }
            row0[ch] = __builtin_bit_cast(uint4, v0);
            row1[ch] = __builtin_bit_cast(uint4, v1);
        }

        // ---- prefetch next row's x (hides under MFMA + stores) ----
        x1v += 9 * 256;
        x2v += 9 * 256;
        if (r != RPB - 1) {
            #pragma unroll
            for (int l = 0; l < 9; ++l) a[l] = x1v[l * 256];
            #pragma unroll
            for (int m = 0; m < 9; ++m) c[m] = x2v[m * 256];
        }

        // ---- MFMA: wave wv, 8 f-tiles x 3 k-slices x 2 n-tiles ----
        f32x4 acc[2][8];
        #pragma unroll
        for (int mt = 0; mt < 2; ++mt)
            #pragma unroll
            for (int ft = 0; ft < 8; ++ft)
                acc[mt][ft] = (f32x4){0.f, 0.f, 0.f, 0.f};

        #pragma unroll
        for (int ft = 0; ft < 8; ++ft) {
            const char* bb = bbase0 + ft * 16 * ROWB;
            #pragma unroll
            for (int ks = 0; ks < 3; ++ks) {
                bf16x8 bfrag = *reinterpret_cast<const bf16x8*>(bb + ks * 64);
                acc[0][ft] = __builtin_amdgcn_mfma_f32_16x16x32_bf16(
                    afrag[0][ks], bfrag, acc[0][ft], 0, 0, 0);
                acc[1][ft] = __builtin_amdgcn_mfma_f32_16x16x32_bf16(
                    afrag[1][ks], bfrag, acc[1][ft], 0, 0, 0);
            }
        }

        // ---- epilogue A: acc -> transposed tile [n][f_local] (S dead) ----
        #pragma unroll
        for (int mt = 0; mt < 2; ++mt) {
            #pragma unroll
            for (int rr = 0; rr < 4; ++rr) {
                const int n = 16 * mt + (lane >> 4) * 4 + rr;
                if (n < D3) {
                    #pragma unroll
                    for (int ft = 0; ft < 8; ++ft)
                        twave[n * TROW + ft * 16 + (lane & 15)]
                            = acc[mt][ft][rr];
                }
            }
        }

        // ---- epilogue B: ONE f32x4 NT store per thread per chunk ----
        // 25 n-rows x 32 quads = 800 quads; per instr: lanes 0-31 one n-row
        // (512B contiguous), lanes 32-63 the next.
        #pragma unroll
        for (int idx = 0; idx < 13; ++idx) {
            const int p = idx * 64 + lane;
            if (p < D3 * 32) {
                const int n = p >> 5;
                const int q = p & 31;
                const f32x4 v = *reinterpret_cast<const f32x4*>(
                    twave + n * TROW + q * 4);
                __builtin_nontemporal_store(
                    v, reinterpret_cast<f32x4*>(op + (size_t)n * MUL + q * 4));
            }
        }
        op += D3 * MUL;
    }
}

extern "C" void kernel_launch(void* const* d_in, const int* in_sizes, int n_in,
                              void* d_out, int out_size, void* d_ws, size_t ws_size,
                              hipStream_t stream) {
    const float* x1 = (const float*)d_in[0];
    const float* x2 = (const float*)d_in[1];
    const float* cg = (const float*)d_in[2];
    float* out = (float*)d_out;

    // allow >64KB dynamic LDS (gfx950 has 160KB/CU); host-side, idempotent,
    // not a stream op -> graph-capture safe
    hipFuncSetAttribute(reinterpret_cast<const void*>(tp_kernel),
                        hipFuncAttributeMaxDynamicSharedMemorySize, SMEM_BYTES);

    dim3 grid(BATCH / RPB);
    dim3 block(256);
    tp_kernel<<<grid, block, SMEM_BYTES, stream>>>(x1, x2, cg, out);
}

// Round 12
// 831.450 us; speedup vs baseline: 1.0145x; 1.0145x over previous
//
#include <hip/hip_runtime.h>

// out[b,n,f] = sum_{l,m} x1[b,l,f] * x2[b,m,f] * cg[l,m,n]
// B=50000, d1=d2=9, d3=25, MUL=512, fp32 in/out.
//
// MFMA formulation: per b, out[n,f] = sum_k W[k,n]*S[k,f], k=(l,m) pad 96;
// S=x1*x2 bf16 in LDS (row per f-channel, pitch 208B); W=cg bf16 regs;
// mfma_f32_16x16x32_bf16 fp32-accum. No barriers: all LDS intra-wave.
//
// Ledger: R7 858 | R8 874 (L2 st) | R9 885 (2-deep pf) | R10 831
// (per-wave transpose epilogue, 4x scalar NT stores) | R11 843 (full-width
// but 1 blk/CU). Occupancy/NT/prefetch/width all <=3% -> BW-pinned at
// ~5.3 TB/s. True traffic 4.4GB (FETCH undercounts reads 2x: 900225 KiB
// == exactly x1 alone); floor ~700us at 6.29 TB/s copy reference -> 84%.
// R12 single change vs R10: epilogue B uses ONE packed f32x4 NT store
// (R10's 4 scalar NT stores may not have merged). If neutral -> roofline.

#define BATCH 50000
#define MUL   512
#define D3    25
#define FCHUNK 256
#define ROWB  208
#define RPB   10

typedef __bf16 bf16x8 __attribute__((ext_vector_type(8)));
typedef float  f32x4  __attribute__((ext_vector_type(4)));

__global__ void __launch_bounds__(256) tp_kernel(
    const float* __restrict__ x1,
    const float* __restrict__ x2,
    const float* __restrict__ cg,
    float* __restrict__ out) {

    extern __shared__ char smem[];

    const int bg    = blockIdx.x >> 1;   // row-group index
    const int chunk = blockIdx.x & 1;    // which 256 f-channels
    const int tid   = threadIdx.x;
    const int lane  = tid & 63;
    const int wv    = tid >> 6;
    const int b0    = bg * RPB;

    // ---- W fragments once per block (cg 8KB, L2-hot after first blocks) ----
    // A[mt][ks]: row n = 16*mt + (lane&15), k = 32*ks + 8*(lane>>4) + j
    bf16x8 afrag[2][3];
    #pragma unroll
    for (int mt = 0; mt < 2; ++mt) {
        const int n = 16 * mt + (lane & 15);
        #pragma unroll
        for (int ks = 0; ks < 3; ++ks) {
            #pragma unroll
            for (int j = 0; j < 8; ++j) {
                const int k = 32 * ks + 8 * (lane >> 4) + j;
                float w = (k < 81 && n < D3) ? cg[k * D3 + n] : 0.0f;
                afrag[mt][ks][j] = (__bf16)w;
            }
        }
    }

    const int fl = chunk * FCHUNK + tid;               // this thread's channel
    const float* x1p = x1 + (size_t)b0 * (9 * MUL) + fl;
    const float* x2p = x2 + (size_t)b0 * (9 * MUL) + fl;
    // per-wave output base: row n=0, f = chunk*256 + wv*64
    float* op = out + (size_t)b0 * (D3 * MUL) + chunk * FCHUNK + wv * 64;

    float a[9], c[9];
    #pragma unroll
    for (int l = 0; l < 9; ++l) a[l] = x1p[l * MUL];
    #pragma unroll
    for (int m = 0; m < 9; ++m) c[m] = x2p[m * MUL];

    uint4* row = reinterpret_cast<uint4*>(smem + tid * ROWB);
    const char* bbase0 = smem + (size_t)(wv * 64 + (lane & 15)) * ROWB
                              + (lane >> 4) * 16;
    // wave's private LDS region, reused for the transposed output tile
    float* twave = reinterpret_cast<float*>(smem + (size_t)wv * 64 * ROWB);

    for (int r = 0; r < RPB; ++r) {
        // ---- S products (row r) -> bf16 -> own LDS row (96 k + pad) ----
        #pragma unroll
        for (int ch = 0; ch < 12; ++ch) {
            bf16x8 v;
            #pragma unroll
            for (int j = 0; j < 8; ++j) {
                const int k = ch * 8 + j;
                const float p = (k < 81) ? a[k / 9] * c[k % 9] : 0.0f;
                v[j] = (__bf16)p;
            }
            row[ch] = __builtin_bit_cast(uint4, v);
        }

        // ---- prefetch next row's x (latency hides under MFMA below) ----
        x1p += 9 * MUL;
        x2p += 9 * MUL;
        if (r != RPB - 1) {
            #pragma unroll
            for (int l = 0; l < 9; ++l) a[l] = x1p[l * MUL];
            #pragma unroll
            for (int m = 0; m < 9; ++m) c[m] = x2p[m * MUL];
        }

        // ---- B fragments from own rows, MFMA ----
        f32x4 acc[2][4];
        #pragma unroll
        for (int mt = 0; mt < 2; ++mt)
            #pragma unroll
            for (int ft = 0; ft < 4; ++ft)
                acc[mt][ft] = (f32x4){0.f, 0.f, 0.f, 0.f};

        #pragma unroll
        for (int ft = 0; ft < 4; ++ft) {
            const char* bb = bbase0 + ft * 16 * ROWB;
            #pragma unroll
            for (int ks = 0; ks < 3; ++ks) {
                bf16x8 bfrag = *reinterpret_cast<const bf16x8*>(bb + ks * 64);
                acc[0][ft] = __builtin_amdgcn_mfma_f32_16x16x32_bf16(
                    afrag[0][ks], bfrag, acc[0][ft], 0, 0, 0);
                acc[1][ft] = __builtin_amdgcn_mfma_f32_16x16x32_bf16(
                    afrag[1][ks], bfrag, acc[1][ft], 0, 0, 0);
            }
        }

        // ---- epilogue A: acc -> wave's LDS tile [n][f_local] (S is dead) ----
        #pragma unroll
        for (int mt = 0; mt < 2; ++mt) {
            #pragma unroll
            for (int rr = 0; rr < 4; ++rr) {
                const int n = 16 * mt + (lane >> 4) * 4 + rr;
                if (n < D3) {
                    #pragma unroll
                    for (int ft = 0; ft < 4; ++ft)
                        twave[n * 64 + ft * 16 + (lane & 15)] = acc[mt][ft][rr];
                }
            }
        }

        // ---- epilogue B: ONE packed f32x4 NT store per thread per quad ----
        #pragma unroll
        for (int idx = 0; idx < 7; ++idx) {
            const int p = idx * 64 + lane;        // 400 = 25 rows x 16 quads
            if (p < D3 * 16) {
                const int n = p >> 4;
                const int q = p & 15;
                const f32x4 v = *reinterpret_cast<const f32x4*>(
                    twave + n * 64 + q * 4);
                __builtin_nontemporal_store(
                    v, reinterpret_cast<f32x4*>(op + (size_t)n * MUL + q * 4));
            }
        }
        op += D3 * MUL;
    }
}

extern "C" void kernel_launch(void* const* d_in, const int* in_sizes, int n_in,
                              void* d_out, int out_size, void* d_ws, size_t ws_size,
                              hipStream_t stream) {
    const float* x1 = (const float*)d_in[0];
    const float* x2 = (const float*)d_in[1];
    const float* cg = (const float*)d_in[2];
    float* out = (float*)d_out;

    dim3 grid((BATCH / RPB) * 2);
    dim3 block(256);
    tp_kernel<<<grid, block, FCHUNK * ROWB, stream>>>(x1, x2, cg, out);
}